// Round 14
// baseline (225.948 us; speedup 1.0000x reference)
//
#include <hip/hip_runtime.h>
#include <math.h>

#define D_MODEL 1024
#define RANK    64
#define PMAX    16
#define S_LEN   1024
#define HD      64
#define MROWS   4096   // B*S
#define NHEAD   16
#define BATCH   4
#define KCMAX   (PMAX * RANK)   // 1024: max composed inner dim
#define NCVBLK  5120            // convert blocks: (4096*1024 + 1024*1024)/4/256

typedef short short8v __attribute__((ext_vector_type(8)));
typedef short short4v __attribute__((ext_vector_type(4)));
typedef float floatx4 __attribute__((ext_vector_type(4)));

typedef __attribute__((address_space(1))) const unsigned int* gptr_t;
typedef __attribute__((address_space(3))) unsigned int* lptr_t;
typedef __attribute__((address_space(3))) short* lds3s;

// async global->LDS, 16 bytes per lane (global_load_lds_dwordx4)
static __device__ __forceinline__ void async16(const void* g, void* l) {
    __builtin_amdgcn_global_load_lds((gptr_t)g, (lptr_t)l, 16, 0, 0);
}

// fp32 -> bf16 bits, round-to-nearest-even (finite inputs only)
static __device__ __forceinline__ short f2bf(float f) {
    unsigned int u = __float_as_uint(f);
    u = (u + 0x7fffu + ((u >> 16) & 1u)) >> 16;
    return (short)u;
}

// ---------------------------------------------------------------------------
// Fused front-end: convert (x, out_w -> bf16) blocks + prep blocks in ONE
// launch.  bid < NCVBLK: elementwise fp32->bf16.  bid >= NCVBLK: prep --
//   z 0..2: Uc[bank][d][j*64+r] = U_bank[p_j][d][r]      (direct gather)
//   z 3..5: Vt[bank][n][j*64+r] = w_j * V_bank[p_j][r][n] (LDS transpose)
// top-k + softmax weight recomputed per block (uniform, deterministic).
// ---------------------------------------------------------------------------
__global__ __launch_bounds__(256) void front_kernel(
    const float* __restrict__ x,  short* __restrict__ xb,
    const float* __restrict__ ow, short* __restrict__ wb,
    const float* __restrict__ qU, const float* __restrict__ kU,
    const float* __restrict__ vU,
    const float* __restrict__ qV, const float* __restrict__ kV,
    const float* __restrict__ vV,
    const float* __restrict__ ql, const float* __restrict__ kl,
    const float* __restrict__ vl,
    const int* __restrict__ topk,
    short* __restrict__ Uc, short* __restrict__ Vt) {
    const int bid = blockIdx.x;
    const int t   = threadIdx.x;
    __shared__ float T[64][65];

    if (bid < NCVBLK) {
        // ---- convert path ----
        int i = bid * 256 + t;
        const int NX = MROWS * D_MODEL / 4;
        const float* src;
        short* dst;
        if (i < NX) { src = x; dst = xb; }
        else        { i -= NX; src = ow; dst = wb; }
        float4 f = ((const float4*)src)[i];
        short4 o;
        o.x = f2bf(f.x); o.y = f2bf(f.y); o.z = f2bf(f.z); o.w = f2bf(f.w);
        ((short4*)dst)[i] = o;
        return;
    }

    // ---- prep path ----
    const int id2  = bid - NCVBLK;
    const int tile = id2 & 15;         // 0..15
    const int j    = (id2 >> 4) & 15;  // 0..15
    const int z    = id2 >> 8;         // 0..5
    int K = *topk; if (K < 1) K = 1; if (K > PMAX) K = PMAX;
    if (j >= K) return;                // unused primitive slot (uniform)
    const int bank = (z < 3) ? z : z - 3;

    // inline top-k + renormalized softmax weight (uniform per block)
    const float* lg = (bank == 0) ? ql : (bank == 1) ? kl : vl;
    float l[PMAX];
    bool used[PMAX];
    for (int i = 0; i < PMAX; ++i) { l[i] = lg[i]; used[i] = false; }
    int   si[PMAX];
    float sl[PMAX];
    for (int jj = 0; jj < K; ++jj) {
        int best = -1; float bv = -INFINITY;
        for (int i = 0; i < PMAX; ++i)
            if (!used[i] && l[i] > bv) { bv = l[i]; best = i; }
        used[best] = true; si[jj] = best; sl[jj] = bv;
    }
    float mx = sl[0], sum = 0.f, ej = 0.f;
    for (int jj = 0; jj < K; ++jj) {
        float e = __expf(sl[jj] - mx);
        sum += e;
        if (jj == j) ej = e;
    }
    const int   p  = si[j];
    const float wj = ej / sum;

    if (z < 3) {
        const float* U = (bank == 0) ? qU : (bank == 1) ? kU : vU;
        const float* src = U + (size_t)p * D_MODEL * RANK;
        short* dst = Uc + (size_t)bank * D_MODEL * KCMAX;
        int r4 = (t & 15) * 4;
        int dl = t >> 4;
#pragma unroll
        for (int i = 0; i < 4; ++i) {
            int d = tile * 64 + i * 16 + dl;
            float4 f = *(const float4*)&src[(size_t)d * RANK + r4];
            short4 o;
            o.x = f2bf(f.x); o.y = f2bf(f.y); o.z = f2bf(f.z); o.w = f2bf(f.w);
            *(short4*)&dst[(size_t)d * KCMAX + j * 64 + r4] = o;
        }
    } else {
        const float* V = (bank == 0) ? qV : (bank == 1) ? kV : vV;
        const float* src = V + (size_t)p * RANK * D_MODEL;    // [r][n]
        int n0 = tile * 64;
        int nl = t & 63, rq = t >> 6;
#pragma unroll
        for (int i = 0; i < 16; ++i) {
            int rl = i * 4 + rq;
            T[nl][rl] = src[(size_t)rl * D_MODEL + n0 + nl] * wj;
        }
        __syncthreads();
        short* dst = Vt + (size_t)bank * D_MODEL * KCMAX;
        int rr = t >> 2;
#pragma unroll
        for (int i = 0; i < 4; ++i) {
            int c = (t & 3) * 16 + i * 4;
            short4 o;
            o.x = f2bf(T[rr][c + 0]); o.y = f2bf(T[rr][c + 1]);
            o.z = f2bf(T[rr][c + 2]); o.w = f2bf(T[rr][c + 3]);
            *(short4*)&dst[(size_t)(n0 + rr) * KCMAX + j * 64 + c] = o;
        }
    }
}

// ---------------------------------------------------------------------------
// bf16 MFMA GEMM tile body, BK=64: C[128x128] += A[128xkl] * B^T[128xkl].
// XOR-swizzled LDS (source-preswizzled for global_load_lds, read XOR'd) so
// the 128B-row-stride ds_read_b128 is conflict-free. kl % 64 == 0.
// ---------------------------------------------------------------------------
static __device__ __forceinline__ void mfma_gemm_tile(
    const short* __restrict__ A, const short* __restrict__ B, int kl,
    int lda, int ldb, int m0, int n0, short* As, short* Bs, floatx4 acc[4][4]) {
    const int t    = threadIdx.x;
    const int w    = t >> 6;
    const int lane = t & 63;
    const int wm   = w & 1, wn = w >> 1;
    const int colL = lane & 15, quad = lane >> 4;
    const int c7   = colL & 7;
    const int sw0  = (quad ^ c7) * 8;          // read swizzle, kk=0 (shorts)
    const int sw1  = ((4 + quad) ^ c7) * 8;    // read swizzle, kk=1

    // staging decode: chunk c = t + it*256; LDS[row][lc] = G[row][lc^(row&7)]
    int srow[4], sck[4];
#pragma unroll
    for (int it = 0; it < 4; ++it) {
        int c = t + it * 256;
        srow[it] = c >> 3;                          // 0..127
        sck[it]  = (((c & 7) ^ ((c >> 3) & 7))) * 8; // source chunk (shorts)
    }

#pragma unroll
    for (int i = 0; i < 4; ++i)
#pragma unroll
        for (int j = 0; j < 4; ++j) acc[i][j] = (floatx4){0.f, 0.f, 0.f, 0.f};

    for (int k0 = 0; k0 < kl; k0 += 64) {
#pragma unroll
        for (int it = 0; it < 4; ++it) {
            async16(A + (size_t)(m0 + srow[it]) * lda + k0 + sck[it],
                    As + (t + it * 256) * 8);
            async16(B + (size_t)(n0 + srow[it]) * ldb + k0 + sck[it],
                    Bs + (t + it * 256) * 8);
        }
        __syncthreads();
#pragma unroll
        for (int kk = 0; kk < 2; ++kk) {
            const int swk = kk ? sw1 : sw0;
            short8v af[4], bf[4];
#pragma unroll
            for (int i = 0; i < 4; ++i)
                af[i] = *(const short8v*)&As[(wm * 64 + i * 16 + colL) * 64 + swk];
#pragma unroll
            for (int j = 0; j < 4; ++j)
                bf[j] = *(const short8v*)&Bs[(wn * 64 + j * 16 + colL) * 64 + swk];
#pragma unroll
            for (int i = 0; i < 4; ++i)
#pragma unroll
                for (int j = 0; j < 4; ++j)
                    acc[i][j] = __builtin_amdgcn_mfma_f32_16x16x32_bf16(af[i], bf[j], acc[i][j], 0, 0, 0);
        }
        __syncthreads();
    }
}

// ---------------------------------------------------------------------------
// Kernel 1: Wt[bank][n][d] = W_eff^T = Vt(as A) x Uc(as B), inner K*64.
// ---------------------------------------------------------------------------
__global__ __launch_bounds__(256) void gemm_weff_kernel(
    const short* __restrict__ Vt, const short* __restrict__ Uc,
    const int* __restrict__ topk, short* __restrict__ Wt) {
    int K = *topk; if (K < 1) K = 1; if (K > PMAX) K = PMAX;
    int id = blockIdx.x + 8 * (blockIdx.y + 8 * blockIdx.z);
    int sw = (id & 7) * 24 + (id >> 3);
    int m0 = (sw & 7) * 128; int rest = sw >> 3;
    int n0 = (rest & 7) * 128; int bank = rest >> 3;
    __shared__ short As[128 * 64];
    __shared__ short Bs[128 * 64];
    floatx4 acc[4][4];
    mfma_gemm_tile(Vt + (size_t)bank * D_MODEL * KCMAX,
                   Uc + (size_t)bank * D_MODEL * KCMAX,
                   K * 64, KCMAX, KCMAX, m0, n0, As, Bs, acc);

    const int t = threadIdx.x, w = t >> 6, lane = t & 63;
    const int wm = w & 1, wn = w >> 1, colL = lane & 15, quad = lane >> 4;
    short* Wb = Wt + (size_t)bank * D_MODEL * D_MODEL;
#pragma unroll
    for (int i = 0; i < 4; ++i)
#pragma unroll
        for (int j = 0; j < 4; ++j)
#pragma unroll
            for (int r = 0; r < 4; ++r)
                Wb[(size_t)(m0 + wm * 64 + i * 16 + quad * 4 + r) * D_MODEL +
                   (n0 + wn * 64 + j * 16 + colL)] = f2bf(acc[i][j][r]);
}

// ---------------------------------------------------------------------------
// Kernel 2: qkv[bank] = x @ W_eff[bank] -> bf16 [3][B*H][S][D]
// ---------------------------------------------------------------------------
__global__ __launch_bounds__(256) void gemm_qkv_kernel(
    const short* __restrict__ xb, const short* __restrict__ Wt,
    short* __restrict__ qkv) {
    int id = blockIdx.x + 32 * (blockIdx.y + 8 * blockIdx.z);
    int sw = (id & 7) * 96 + (id >> 3);
    int m0 = (sw & 31) * 128; int rest = sw >> 5;
    int n0 = (rest & 7) * 128; int bank = rest >> 3;
    __shared__ short As[128 * 64];
    __shared__ short Bs[128 * 64];
    floatx4 acc[4][4];
    mfma_gemm_tile(xb, Wt + (size_t)bank * D_MODEL * D_MODEL,
                   D_MODEL, D_MODEL, D_MODEL, m0, n0, As, Bs, acc);

    const int t = threadIdx.x, w = t >> 6, lane = t & 63;
    const int wm = w & 1, wn = w >> 1, colL = lane & 15, quad = lane >> 4;
    short* outp = qkv + (size_t)bank * MROWS * D_MODEL;
#pragma unroll
    for (int i = 0; i < 4; ++i)
#pragma unroll
        for (int j = 0; j < 4; ++j)
#pragma unroll
            for (int r = 0; r < 4; ++r) {
                int m = m0 + wm * 64 + i * 16 + quad * 4 + r;
                int n = n0 + wn * 64 + j * 16 + colL;
                int b = m >> 10, s = m & 1023;
                int head = n >> 6, d = n & 63;
                outp[(((size_t)(b * NHEAD + head) << 10) + s) * HD + d] = f2bf(acc[i][j][r]);
            }
}

// ---------------------------------------------------------------------------
// Kernel 4: out = attn(bf16) @ out_w(bf16)^T -> fp32 d_out (128x128)
// ---------------------------------------------------------------------------
__global__ __launch_bounds__(256) void gemm_proj_kernel(
    const short* __restrict__ attnb, const short* __restrict__ wb,
    float* __restrict__ outp) {
    // XCD-aware swizzle: 256 blocks, chunk 32 per XCD
    int id = blockIdx.x + 32 * blockIdx.y;
    int sw = (id & 7) * 32 + (id >> 3);
    int m0 = (sw & 31) * 128;
    int n0 = (sw >> 5) * 128;
    __shared__ short As[128 * 64];
    __shared__ short Bs[128 * 64];
    floatx4 acc[4][4];
    mfma_gemm_tile(attnb, wb, D_MODEL, D_MODEL, D_MODEL, m0, n0, As, Bs, acc);

    const int t = threadIdx.x, w = t >> 6, lane = t & 63;
    const int wm = w & 1, wn = w >> 1, colL = lane & 15, quad = lane >> 4;
#pragma unroll
    for (int i = 0; i < 4; ++i)
#pragma unroll
        for (int j = 0; j < 4; ++j)
#pragma unroll
            for (int r = 0; r < 4; ++r)
                outp[(size_t)(m0 + wm * 64 + i * 16 + quad * 4 + r) * D_MODEL +
                     (n0 + wn * 64 + j * 16 + colL)] = acc[i][j][r];
}

// ---------------------------------------------------------------------------
// Kernel 3: causal flash attention, swapped-operand QK^T (P stays in regs).
// ONE q-tile per block: grid 1024 = 4 blocks/CU (vs paired 512 = 2/CU) to
// double occupancy. Chunked XCD swizzle keeps 8 heads per XCD (KV L2-resident
// -- the R2 regression was missing this, FETCH 55MB; R3's swizzle fixed it).
// Heavy tiles (qt=15) dispatch first for load balance.
// ---------------------------------------------------------------------------
__global__ __launch_bounds__(256) void attn_mfma_kernel(
    const short* __restrict__ qkv,    // bf16 [3][BH=64][S=1024][D=64]
    short* __restrict__ attn_out) {   // bf16 [B=4][S=1024][H*D=1024]
    const int t    = threadIdx.x;
    const int w    = t >> 6;
    const int lane = t & 63;
    const int col  = lane & 15;
    const int quad = lane >> 4;
    // chunked XCD swizzle: 1024 blocks, 128 per XCD -> 8 heads per XCD;
    // within a chunk qt descends (heavy first).
    int id  = blockIdx.x + 16 * blockIdx.y;          // 0..1023
    int sw  = (id & 7) * 128 + (id >> 3);
    const int bh = sw >> 4;          // 0..63
    const int qt = 15 - (sw & 15);   // 15..0, heavy first
    const size_t HS   = (size_t)S_LEN * HD;
    const size_t BSTR = (size_t)MROWS * D_MODEL;
    const short* Qg = qkv + (size_t)bh * HS;
    const short* Kg = qkv + BSTR + (size_t)bh * HS;
    const short* Vg = qkv + 2 * BSTR + (size_t)bh * HS;

    __shared__ short Ks[128 * 64];   // row-major [key][d], XOR-swizzled slots
    __shared__ short Vs[128 * 64];   // subtiled [d16][k4][4][16]

    const float SC = 0.125f * 1.44269504f;   // 1/sqrt(64) * log2(e)

    // staging decode (loop-invariant): chunk c = t + it*256
    int krow[4], kslot[4], vkey[4], voff[4];
#pragma unroll
    for (int it = 0; it < 4; ++it) {
        int c = t + it * 256;
        krow[it]  = c >> 3;
        kslot[it] = (c & 7) ^ ((c >> 3) & 7);
        int h = c & 1, kr = (c >> 1) & 3, k4 = (c >> 3) & 31, d16 = c >> 8;
        vkey[it] = k4 * 4 + kr;
        voff[it] = d16 * 16 + h * 8;
    }
    const int sw0 = (quad ^ (col & 7)) * 16;          // K read swizzle (bytes)
    const int sw1 = ((4 + quad) ^ (col & 7)) * 16;
    lds3s vb = (lds3s)&Vs[quad * 64 + col * 4];       // tr-read base

    const int qb = qt * 4 + w;
    const int qrow = qt * 64 + w * 16 + col;
    short8v aq0 = *(const short8v*)(Qg + (size_t)qrow * HD + quad * 8);
    short8v aq1 = *(const short8v*)(Qg + (size_t)qrow * HD + 32 + quad * 8);
    floatx4 O0 = {0.f, 0.f, 0.f, 0.f}, O1 = O0, O2 = O0, O3 = O0;
    float mrow = -INFINITY, lrow = 0.f;
    const int nkv = (qt + 2) >> 1;

    for (int jt = 0; jt < nkv; ++jt) {
        __syncthreads();
#pragma unroll
        for (int it = 0; it < 4; ++it) {
            async16(Kg + (size_t)(jt * 128 + krow[it]) * HD + kslot[it] * 8,
                    Ks + (t + it * 256) * 8);
            async16(Vg + (size_t)(jt * 128 + vkey[it]) * HD + voff[it],
                    Vs + (t + it * 256) * 8);
        }
        __syncthreads();

        // ---- swapped QK^T: lane gets S[q=col][key=16mb+quad*4+r] ----
        const int base = jt * 8;
        float s[8][4];
#pragma unroll
        for (int mb = 0; mb < 8; ++mb) {
            int rel = qb - (base + mb);
            if (rel >= 0) {
                floatx4 c4 = {0.f, 0.f, 0.f, 0.f};
                const char* kp = (const char*)Ks + mb * 2048 + col * 128;
                short8v a0 = *(const short8v*)(kp + sw0);
                short8v a1 = *(const short8v*)(kp + sw1);
                c4 = __builtin_amdgcn_mfma_f32_16x16x32_bf16(a0, aq0, c4, 0, 0, 0);
                c4 = __builtin_amdgcn_mfma_f32_16x16x32_bf16(a1, aq1, c4, 0, 0, 0);
#pragma unroll
                for (int r = 0; r < 4; ++r) {
                    float v = c4[r] * SC;
                    if (rel == 0 && quad * 4 + r > col) v = -INFINITY;
                    s[mb][r] = v;
                }
            } else {
#pragma unroll
                for (int r = 0; r < 4; ++r) s[mb][r] = -INFINITY;
            }
        }
        // ---- online softmax, per q-row (q = col), defer-max ----
        float tm = -INFINITY;
#pragma unroll
        for (int mb = 0; mb < 8; ++mb)
#pragma unroll
            for (int r = 0; r < 4; ++r) tm = fmaxf(tm, s[mb][r]);
        tm = fmaxf(tm, __shfl_xor(tm, 16));
        tm = fmaxf(tm, __shfl_xor(tm, 32));
        if (__any(tm > mrow + 8.0f)) {
            float mnew  = fmaxf(mrow, tm);
            float alpha = exp2f(mrow - mnew);
            lrow *= alpha;
            mrow = mnew;
#pragma unroll
            for (int r = 0; r < 4; ++r) {
                float ar = __shfl(alpha, quad * 4 + r);
                O0[r] *= ar; O1[r] *= ar; O2[r] *= ar; O3[r] *= ar;
            }
        }
        float p[8][4];
        float ps = 0.f;
#pragma unroll
        for (int mb = 0; mb < 8; ++mb)
#pragma unroll
            for (int r = 0; r < 4; ++r) {
                float e = exp2f(s[mb][r] - mrow);
                p[mb][r] = e; ps += e;
            }
        ps += __shfl_xor(ps, 16);
        ps += __shfl_xor(ps, 32);
        lrow += ps;

        // ---- PV: A = packed P (in regs), B = V via tr-reads ----
        int lim = qb * 16 + 15 - (jt << 7);
        int ksm = lim >> 5; if (ksm > 3) ksm = 3;
#pragma unroll
        for (int ks = 0; ks < 4; ++ks) {
            if (ks <= ksm) {
                lds3s vc = vb + ks * 512;
                short4v t00, t01, t10, t11, t20, t21, t30, t31;
                asm volatile("ds_read_b64_tr_b16 %0, %1" : "=v"(t00) : "v"(vc));
                asm volatile("ds_read_b64_tr_b16 %0, %1" : "=v"(t01) : "v"(vc + 256));
                asm volatile("ds_read_b64_tr_b16 %0, %1" : "=v"(t10) : "v"(vc + 2048));
                asm volatile("ds_read_b64_tr_b16 %0, %1" : "=v"(t11) : "v"(vc + 2304));
                asm volatile("ds_read_b64_tr_b16 %0, %1" : "=v"(t20) : "v"(vc + 4096));
                asm volatile("ds_read_b64_tr_b16 %0, %1" : "=v"(t21) : "v"(vc + 4352));
                asm volatile("ds_read_b64_tr_b16 %0, %1" : "=v"(t30) : "v"(vc + 6144));
                asm volatile("ds_read_b64_tr_b16 %0, %1" : "=v"(t31) : "v"(vc + 6400));
                short8v ap;
                ap[0] = f2bf(p[2 * ks][0]);     ap[1] = f2bf(p[2 * ks][1]);
                ap[2] = f2bf(p[2 * ks][2]);     ap[3] = f2bf(p[2 * ks][3]);
                ap[4] = f2bf(p[2 * ks + 1][0]); ap[5] = f2bf(p[2 * ks + 1][1]);
                ap[6] = f2bf(p[2 * ks + 1][2]); ap[7] = f2bf(p[2 * ks + 1][3]);
                asm volatile("s_waitcnt lgkmcnt(0)" ::: "memory");
                __builtin_amdgcn_sched_barrier(0);
                short8v bv0 = __builtin_shufflevector(t00, t01, 0, 1, 2, 3, 4, 5, 6, 7);
                short8v bv1 = __builtin_shufflevector(t10, t11, 0, 1, 2, 3, 4, 5, 6, 7);
                short8v bv2 = __builtin_shufflevector(t20, t21, 0, 1, 2, 3, 4, 5, 6, 7);
                short8v bv3 = __builtin_shufflevector(t30, t31, 0, 1, 2, 3, 4, 5, 6, 7);
                O0 = __builtin_amdgcn_mfma_f32_16x16x32_bf16(ap, bv0, O0, 0, 0, 0);
                O1 = __builtin_amdgcn_mfma_f32_16x16x32_bf16(ap, bv1, O1, 0, 0, 0);
                O2 = __builtin_amdgcn_mfma_f32_16x16x32_bf16(ap, bv2, O2, 0, 0, 0);
                O3 = __builtin_amdgcn_mfma_f32_16x16x32_bf16(ap, bv3, O3, 0, 0, 0);
            }
        }
    }
    // ---- epilogue: normalize (redistribute 1/l via shfl) + store ----
    const int b  = bh >> 4;
    const int hh = bh & 15;
    short* orow = attn_out +
        ((size_t)(b * S_LEN) + qt * 64 + w * 16) * D_MODEL + hh * 64;
    float linv = 1.f / lrow;
#pragma unroll
    for (int r = 0; r < 4; ++r) {
        float inv = __shfl(linv, quad * 4 + r);
        short* prw = orow + (size_t)(quad * 4 + r) * D_MODEL;
        prw[0  + col] = f2bf(O0[r] * inv);
        prw[16 + col] = f2bf(O1[r] * inv);
        prw[32 + col] = f2bf(O2[r] * inv);
        prw[48 + col] = f2bf(O3[r] * inv);
    }
}

// ---------------------------------------------------------------------------
extern "C" void kernel_launch(void* const* d_in, const int* in_sizes, int n_in,
                              void* d_out, int out_size, void* d_ws, size_t ws_size,
                              hipStream_t stream) {
    const float* x    = (const float*)d_in[0];
    const float* qU   = (const float*)d_in[1];
    const float* qV   = (const float*)d_in[2];
    const float* kU   = (const float*)d_in[3];
    const float* kV   = (const float*)d_in[4];
    const float* vU   = (const float*)d_in[5];
    const float* vV   = (const float*)d_in[6];
    const float* qlg  = (const float*)d_in[7];
    const float* klg  = (const float*)d_in[8];
    const float* vlg  = (const float*)d_in[9];
    const float* outw = (const float*)d_in[10];
    const int*   topk = (const int*)d_in[11];
    float* outp = (float*)d_out;

    char* ws = (char*)d_ws;
    short* xb   = (short*)(ws + 512);                    // 8 MB
    short* Uc   = xb + (size_t)MROWS * D_MODEL;          // 6 MB [3][1024][KCMAX]
    short* Vt   = Uc + (size_t)3 * D_MODEL * KCMAX;      // 6 MB [3][1024][KCMAX]
    short* wb   = Vt + (size_t)3 * D_MODEL * KCMAX;      // 2 MB
    short* Wt   = wb + (size_t)D_MODEL * D_MODEL;        // 6 MB [3][1024][1024]
    short* qkvb = Wt + (size_t)3 * D_MODEL * D_MODEL;    // 24 MB
    short* attnb = qkvb + (size_t)3 * MROWS * D_MODEL;   // 8 MB

    front_kernel<<<NCVBLK + 16 * 16 * 6, 256, 0, stream>>>(
        x, xb, outw, wb, qU, kU, vU, qV, kV, vV, qlg, klg, vlg, topk, Uc, Vt);
    gemm_weff_kernel<<<dim3(8, 8, 3), 256, 0, stream>>>(Vt, Uc, topk, Wt);
    gemm_qkv_kernel<<<dim3(32, 8, 3), 256, 0, stream>>>(xb, Wt, qkvb);
    attn_mfma_kernel<<<dim3(16, 64), 256, 0, stream>>>(qkvb, attnb);
    gemm_proj_kernel<<<dim3(32, 8), 256, 0, stream>>>(attnb, wb, outp);
}

// Round 15
// 212.718 us; speedup vs baseline: 1.0622x; 1.0622x over previous
//
#include <hip/hip_runtime.h>
#include <math.h>

#define D_MODEL 1024
#define RANK    64
#define PMAX    16
#define S_LEN   1024
#define HD      64
#define MROWS   4096   // B*S
#define NHEAD   16
#define BATCH   4
#define KCMAX   (PMAX * RANK)   // 1024: max composed inner dim
#define NCVBLK  5120            // convert blocks: (4096*1024 + 1024*1024)/4/256

typedef short short8v __attribute__((ext_vector_type(8)));
typedef short short4v __attribute__((ext_vector_type(4)));
typedef float floatx4 __attribute__((ext_vector_type(4)));

typedef __attribute__((address_space(1))) const unsigned int* gptr_t;
typedef __attribute__((address_space(3))) unsigned int* lptr_t;
typedef __attribute__((address_space(3))) short* lds3s;

// async global->LDS, 16 bytes per lane (global_load_lds_dwordx4)
static __device__ __forceinline__ void async16(const void* g, void* l) {
    __builtin_amdgcn_global_load_lds((gptr_t)g, (lptr_t)l, 16, 0, 0);
}

// fp32 -> bf16 bits, round-to-nearest-even (finite inputs only)
static __device__ __forceinline__ short f2bf(float f) {
    unsigned int u = __float_as_uint(f);
    u = (u + 0x7fffu + ((u >> 16) & 1u)) >> 16;
    return (short)u;
}

// ---------------------------------------------------------------------------
// Fused front-end: convert (x, out_w -> bf16) blocks + prep blocks in ONE
// launch.  bid < NCVBLK: elementwise fp32->bf16.  bid >= NCVBLK: prep --
//   z 0..2: Uc[bank][d][j*64+r] = U_bank[p_j][d][r]      (direct gather)
//   z 3..5: Vt[bank][n][j*64+r] = w_j * V_bank[p_j][r][n] (LDS transpose)
// top-k + softmax weight recomputed per block (uniform, deterministic).
// ---------------------------------------------------------------------------
__global__ __launch_bounds__(256) void front_kernel(
    const float* __restrict__ x,  short* __restrict__ xb,
    const float* __restrict__ ow, short* __restrict__ wb,
    const float* __restrict__ qU, const float* __restrict__ kU,
    const float* __restrict__ vU,
    const float* __restrict__ qV, const float* __restrict__ kV,
    const float* __restrict__ vV,
    const float* __restrict__ ql, const float* __restrict__ kl,
    const float* __restrict__ vl,
    const int* __restrict__ topk,
    short* __restrict__ Uc, short* __restrict__ Vt) {
    const int bid = blockIdx.x;
    const int t   = threadIdx.x;
    __shared__ float T[64][65];

    if (bid < NCVBLK) {
        // ---- convert path ----
        int i = bid * 256 + t;
        const int NX = MROWS * D_MODEL / 4;
        const float* src;
        short* dst;
        if (i < NX) { src = x; dst = xb; }
        else        { i -= NX; src = ow; dst = wb; }
        float4 f = ((const float4*)src)[i];
        short4 o;
        o.x = f2bf(f.x); o.y = f2bf(f.y); o.z = f2bf(f.z); o.w = f2bf(f.w);
        ((short4*)dst)[i] = o;
        return;
    }

    // ---- prep path ----
    const int id2  = bid - NCVBLK;
    const int tile = id2 & 15;         // 0..15
    const int j    = (id2 >> 4) & 15;  // 0..15
    const int z    = id2 >> 8;         // 0..5
    int K = *topk; if (K < 1) K = 1; if (K > PMAX) K = PMAX;
    if (j >= K) return;                // unused primitive slot (uniform)
    const int bank = (z < 3) ? z : z - 3;

    // inline top-k + renormalized softmax weight (uniform per block)
    const float* lg = (bank == 0) ? ql : (bank == 1) ? kl : vl;
    float l[PMAX];
    bool used[PMAX];
    for (int i = 0; i < PMAX; ++i) { l[i] = lg[i]; used[i] = false; }
    int   si[PMAX];
    float sl[PMAX];
    for (int jj = 0; jj < K; ++jj) {
        int best = -1; float bv = -INFINITY;
        for (int i = 0; i < PMAX; ++i)
            if (!used[i] && l[i] > bv) { bv = l[i]; best = i; }
        used[best] = true; si[jj] = best; sl[jj] = bv;
    }
    float mx = sl[0], sum = 0.f, ej = 0.f;
    for (int jj = 0; jj < K; ++jj) {
        float e = __expf(sl[jj] - mx);
        sum += e;
        if (jj == j) ej = e;
    }
    const int   p  = si[j];
    const float wj = ej / sum;

    if (z < 3) {
        const float* U = (bank == 0) ? qU : (bank == 1) ? kU : vU;
        const float* src = U + (size_t)p * D_MODEL * RANK;
        short* dst = Uc + (size_t)bank * D_MODEL * KCMAX;
        int r4 = (t & 15) * 4;
        int dl = t >> 4;
#pragma unroll
        for (int i = 0; i < 4; ++i) {
            int d = tile * 64 + i * 16 + dl;
            float4 f = *(const float4*)&src[(size_t)d * RANK + r4];
            short4 o;
            o.x = f2bf(f.x); o.y = f2bf(f.y); o.z = f2bf(f.z); o.w = f2bf(f.w);
            *(short4*)&dst[(size_t)d * KCMAX + j * 64 + r4] = o;
        }
    } else {
        const float* V = (bank == 0) ? qV : (bank == 1) ? kV : vV;
        const float* src = V + (size_t)p * RANK * D_MODEL;    // [r][n]
        int n0 = tile * 64;
        int nl = t & 63, rq = t >> 6;
#pragma unroll
        for (int i = 0; i < 16; ++i) {
            int rl = i * 4 + rq;
            T[nl][rl] = src[(size_t)rl * D_MODEL + n0 + nl] * wj;
        }
        __syncthreads();
        short* dst = Vt + (size_t)bank * D_MODEL * KCMAX;
        int rr = t >> 2;
#pragma unroll
        for (int i = 0; i < 4; ++i) {
            int c = (t & 3) * 16 + i * 4;
            short4 o;
            o.x = f2bf(T[rr][c + 0]); o.y = f2bf(T[rr][c + 1]);
            o.z = f2bf(T[rr][c + 2]); o.w = f2bf(T[rr][c + 3]);
            *(short4*)&dst[(size_t)(n0 + rr) * KCMAX + j * 64 + c] = o;
        }
    }
}

// ---------------------------------------------------------------------------
// bf16 MFMA GEMM tile body, BK=64: C[128x128] += A[128xkl] * B^T[128xkl].
// XOR-swizzled LDS (source-preswizzled for global_load_lds, read XOR'd) so
// the 128B-row-stride ds_read_b128 is conflict-free. kl % 64 == 0.
// ---------------------------------------------------------------------------
static __device__ __forceinline__ void mfma_gemm_tile(
    const short* __restrict__ A, const short* __restrict__ B, int kl,
    int lda, int ldb, int m0, int n0, short* As, short* Bs, floatx4 acc[4][4]) {
    const int t    = threadIdx.x;
    const int w    = t >> 6;
    const int lane = t & 63;
    const int wm   = w & 1, wn = w >> 1;
    const int colL = lane & 15, quad = lane >> 4;
    const int c7   = colL & 7;
    const int sw0  = (quad ^ c7) * 8;          // read swizzle, kk=0 (shorts)
    const int sw1  = ((4 + quad) ^ c7) * 8;    // read swizzle, kk=1

    // staging decode: chunk c = t + it*256; LDS[row][lc] = G[row][lc^(row&7)]
    int srow[4], sck[4];
#pragma unroll
    for (int it = 0; it < 4; ++it) {
        int c = t + it * 256;
        srow[it] = c >> 3;                          // 0..127
        sck[it]  = (((c & 7) ^ ((c >> 3) & 7))) * 8; // source chunk (shorts)
    }

#pragma unroll
    for (int i = 0; i < 4; ++i)
#pragma unroll
        for (int j = 0; j < 4; ++j) acc[i][j] = (floatx4){0.f, 0.f, 0.f, 0.f};

    for (int k0 = 0; k0 < kl; k0 += 64) {
#pragma unroll
        for (int it = 0; it < 4; ++it) {
            async16(A + (size_t)(m0 + srow[it]) * lda + k0 + sck[it],
                    As + (t + it * 256) * 8);
            async16(B + (size_t)(n0 + srow[it]) * ldb + k0 + sck[it],
                    Bs + (t + it * 256) * 8);
        }
        __syncthreads();
#pragma unroll
        for (int kk = 0; kk < 2; ++kk) {
            const int swk = kk ? sw1 : sw0;
            short8v af[4], bf[4];
#pragma unroll
            for (int i = 0; i < 4; ++i)
                af[i] = *(const short8v*)&As[(wm * 64 + i * 16 + colL) * 64 + swk];
#pragma unroll
            for (int j = 0; j < 4; ++j)
                bf[j] = *(const short8v*)&Bs[(wn * 64 + j * 16 + colL) * 64 + swk];
#pragma unroll
            for (int i = 0; i < 4; ++i)
#pragma unroll
                for (int j = 0; j < 4; ++j)
                    acc[i][j] = __builtin_amdgcn_mfma_f32_16x16x32_bf16(af[i], bf[j], acc[i][j], 0, 0, 0);
        }
        __syncthreads();
    }
}

// ---------------------------------------------------------------------------
// Kernel 1: Wt[bank][n][d] = W_eff^T = Vt(as A) x Uc(as B), inner K*64.
// ---------------------------------------------------------------------------
__global__ __launch_bounds__(256) void gemm_weff_kernel(
    const short* __restrict__ Vt, const short* __restrict__ Uc,
    const int* __restrict__ topk, short* __restrict__ Wt) {
    int K = *topk; if (K < 1) K = 1; if (K > PMAX) K = PMAX;
    int id = blockIdx.x + 8 * (blockIdx.y + 8 * blockIdx.z);
    int sw = (id & 7) * 24 + (id >> 3);
    int m0 = (sw & 7) * 128; int rest = sw >> 3;
    int n0 = (rest & 7) * 128; int bank = rest >> 3;
    __shared__ short As[128 * 64];
    __shared__ short Bs[128 * 64];
    floatx4 acc[4][4];
    mfma_gemm_tile(Vt + (size_t)bank * D_MODEL * KCMAX,
                   Uc + (size_t)bank * D_MODEL * KCMAX,
                   K * 64, KCMAX, KCMAX, m0, n0, As, Bs, acc);

    const int t = threadIdx.x, w = t >> 6, lane = t & 63;
    const int wm = w & 1, wn = w >> 1, colL = lane & 15, quad = lane >> 4;
    short* Wb = Wt + (size_t)bank * D_MODEL * D_MODEL;
#pragma unroll
    for (int i = 0; i < 4; ++i)
#pragma unroll
        for (int j = 0; j < 4; ++j)
#pragma unroll
            for (int r = 0; r < 4; ++r)
                Wb[(size_t)(m0 + wm * 64 + i * 16 + quad * 4 + r) * D_MODEL +
                   (n0 + wn * 64 + j * 16 + colL)] = f2bf(acc[i][j][r]);
}

// ---------------------------------------------------------------------------
// Kernel 2: qkv[bank] = x @ W_eff[bank] -> bf16 [3][B*H][S][D]
// ---------------------------------------------------------------------------
__global__ __launch_bounds__(256) void gemm_qkv_kernel(
    const short* __restrict__ xb, const short* __restrict__ Wt,
    short* __restrict__ qkv) {
    int id = blockIdx.x + 32 * (blockIdx.y + 8 * blockIdx.z);
    int sw = (id & 7) * 96 + (id >> 3);
    int m0 = (sw & 31) * 128; int rest = sw >> 5;
    int n0 = (rest & 7) * 128; int bank = rest >> 3;
    __shared__ short As[128 * 64];
    __shared__ short Bs[128 * 64];
    floatx4 acc[4][4];
    mfma_gemm_tile(xb, Wt + (size_t)bank * D_MODEL * D_MODEL,
                   D_MODEL, D_MODEL, D_MODEL, m0, n0, As, Bs, acc);

    const int t = threadIdx.x, w = t >> 6, lane = t & 63;
    const int wm = w & 1, wn = w >> 1, colL = lane & 15, quad = lane >> 4;
    short* outp = qkv + (size_t)bank * MROWS * D_MODEL;
#pragma unroll
    for (int i = 0; i < 4; ++i)
#pragma unroll
        for (int j = 0; j < 4; ++j)
#pragma unroll
            for (int r = 0; r < 4; ++r) {
                int m = m0 + wm * 64 + i * 16 + quad * 4 + r;
                int n = n0 + wn * 64 + j * 16 + colL;
                int b = m >> 10, s = m & 1023;
                int head = n >> 6, d = n & 63;
                outp[(((size_t)(b * NHEAD + head) << 10) + s) * HD + d] = f2bf(acc[i][j][r]);
            }
}

// ---------------------------------------------------------------------------
// Kernel 4: out = attn(bf16) @ out_w(bf16)^T -> fp32 d_out (128x128)
// ---------------------------------------------------------------------------
__global__ __launch_bounds__(256) void gemm_proj_kernel(
    const short* __restrict__ attnb, const short* __restrict__ wb,
    float* __restrict__ outp) {
    // XCD-aware swizzle: 256 blocks, chunk 32 per XCD
    int id = blockIdx.x + 32 * blockIdx.y;
    int sw = (id & 7) * 32 + (id >> 3);
    int m0 = (sw & 31) * 128;
    int n0 = (sw >> 5) * 128;
    __shared__ short As[128 * 64];
    __shared__ short Bs[128 * 64];
    floatx4 acc[4][4];
    mfma_gemm_tile(attnb, wb, D_MODEL, D_MODEL, D_MODEL, m0, n0, As, Bs, acc);

    const int t = threadIdx.x, w = t >> 6, lane = t & 63;
    const int wm = w & 1, wn = w >> 1, colL = lane & 15, quad = lane >> 4;
#pragma unroll
    for (int i = 0; i < 4; ++i)
#pragma unroll
        for (int j = 0; j < 4; ++j)
#pragma unroll
            for (int r = 0; r < 4; ++r)
                outp[(size_t)(m0 + wm * 64 + i * 16 + quad * 4 + r) * D_MODEL +
                     (n0 + wn * 64 + j * 16 + colL)] = acc[i][j][r];
}

// ---------------------------------------------------------------------------
// Kernel 3: causal flash attention, swapped-operand QK^T (P stays in regs).
// PAIRED 2-phase (qt = pr, 15-pr): uniform 9 kv-tiles per block -- R14 showed
// load uniformity beats nominal blocks/CU (unpaired: occupancy DROPPED to
// 12.5%, dur 47.9us). Verified structure from R9 (215.6us total).
// ---------------------------------------------------------------------------
__global__ __launch_bounds__(256) void attn_mfma_kernel(
    const short* __restrict__ qkv,    // bf16 [3][BH=64][S=1024][D=64]
    short* __restrict__ attn_out) {   // bf16 [B=4][S=1024][H*D=1024]
    const int t    = threadIdx.x;
    const int w    = t >> 6;
    const int lane = t & 63;
    const int col  = lane & 15;
    const int quad = lane >> 4;
    // XCD swizzle: 512 blocks, chunk 64 -> 8 heads per XCD (KV stays in L2)
    int id = blockIdx.x + 8 * blockIdx.y;
    int swz = (id & 7) * 64 + (id >> 3);
    const int pr = swz & 7;    // 0..7
    const int bh = swz >> 3;   // 0..63
    const size_t HS   = (size_t)S_LEN * HD;
    const size_t BSTR = (size_t)MROWS * D_MODEL;
    const short* Qg = qkv + (size_t)bh * HS;
    const short* Kg = qkv + BSTR + (size_t)bh * HS;
    const short* Vg = qkv + 2 * BSTR + (size_t)bh * HS;

    __shared__ short Ks[128 * 64];   // row-major [key][d], XOR-swizzled slots
    __shared__ short Vs[128 * 64];   // subtiled [d16][k4][4][16]

    const float SC = 0.125f * 1.44269504f;   // 1/sqrt(64) * log2(e)

    // staging decode (loop-invariant): chunk c = t + it*256
    int krow[4], kslot[4], vkey[4], voff[4];
#pragma unroll
    for (int it = 0; it < 4; ++it) {
        int c = t + it * 256;
        krow[it]  = c >> 3;
        kslot[it] = (c & 7) ^ ((c >> 3) & 7);
        int h = c & 1, kr = (c >> 1) & 3, k4 = (c >> 3) & 31, d16 = c >> 8;
        vkey[it] = k4 * 4 + kr;
        voff[it] = d16 * 16 + h * 8;
    }
    const int sw0 = (quad ^ (col & 7)) * 16;          // K read swizzle (bytes)
    const int sw1 = ((4 + quad) ^ (col & 7)) * 16;
    lds3s vb = (lds3s)&Vs[quad * 64 + col * 4];       // tr-read base

    for (int ph = 0; ph < 2; ++ph) {
        const int qt = ph ? (15 - pr) : pr;
        const int qb = qt * 4 + w;
        const int qrow = qt * 64 + w * 16 + col;
        short8v aq0 = *(const short8v*)(Qg + (size_t)qrow * HD + quad * 8);
        short8v aq1 = *(const short8v*)(Qg + (size_t)qrow * HD + 32 + quad * 8);
        floatx4 O0 = {0.f, 0.f, 0.f, 0.f}, O1 = O0, O2 = O0, O3 = O0;
        float mrow = -INFINITY, lrow = 0.f;
        const int nkv = (qt + 2) >> 1;

        for (int jt = 0; jt < nkv; ++jt) {
            __syncthreads();
#pragma unroll
            for (int it = 0; it < 4; ++it) {
                async16(Kg + (size_t)(jt * 128 + krow[it]) * HD + kslot[it] * 8,
                        Ks + (t + it * 256) * 8);
                async16(Vg + (size_t)(jt * 128 + vkey[it]) * HD + voff[it],
                        Vs + (t + it * 256) * 8);
            }
            __syncthreads();

            // ---- swapped QK^T: lane gets S[q=col][key=16mb+quad*4+r] ----
            const int base = jt * 8;
            float s[8][4];
#pragma unroll
            for (int mb = 0; mb < 8; ++mb) {
                int rel = qb - (base + mb);
                if (rel >= 0) {
                    floatx4 c4 = {0.f, 0.f, 0.f, 0.f};
                    const char* kp = (const char*)Ks + mb * 2048 + col * 128;
                    short8v a0 = *(const short8v*)(kp + sw0);
                    short8v a1 = *(const short8v*)(kp + sw1);
                    c4 = __builtin_amdgcn_mfma_f32_16x16x32_bf16(a0, aq0, c4, 0, 0, 0);
                    c4 = __builtin_amdgcn_mfma_f32_16x16x32_bf16(a1, aq1, c4, 0, 0, 0);
#pragma unroll
                    for (int r = 0; r < 4; ++r) {
                        float v = c4[r] * SC;
                        if (rel == 0 && quad * 4 + r > col) v = -INFINITY;
                        s[mb][r] = v;
                    }
                } else {
#pragma unroll
                    for (int r = 0; r < 4; ++r) s[mb][r] = -INFINITY;
                }
            }
            // ---- online softmax, per q-row (q = col), defer-max ----
            float tm = -INFINITY;
#pragma unroll
            for (int mb = 0; mb < 8; ++mb)
#pragma unroll
                for (int r = 0; r < 4; ++r) tm = fmaxf(tm, s[mb][r]);
            tm = fmaxf(tm, __shfl_xor(tm, 16));
            tm = fmaxf(tm, __shfl_xor(tm, 32));
            if (__any(tm > mrow + 8.0f)) {
                float mnew  = fmaxf(mrow, tm);
                float alpha = exp2f(mrow - mnew);
                lrow *= alpha;
                mrow = mnew;
#pragma unroll
                for (int r = 0; r < 4; ++r) {
                    float ar = __shfl(alpha, quad * 4 + r);
                    O0[r] *= ar; O1[r] *= ar; O2[r] *= ar; O3[r] *= ar;
                }
            }
            float p[8][4];
            float ps = 0.f;
#pragma unroll
            for (int mb = 0; mb < 8; ++mb)
#pragma unroll
                for (int r = 0; r < 4; ++r) {
                    float e = exp2f(s[mb][r] - mrow);
                    p[mb][r] = e; ps += e;
                }
            ps += __shfl_xor(ps, 16);
            ps += __shfl_xor(ps, 32);
            lrow += ps;

            // ---- PV: A = packed P (in regs), B = V via tr-reads ----
            int lim = qb * 16 + 15 - (jt << 7);
            int ksm = lim >> 5; if (ksm > 3) ksm = 3;
#pragma unroll
            for (int ks = 0; ks < 4; ++ks) {
                if (ks <= ksm) {
                    lds3s vc = vb + ks * 512;
                    short4v t00, t01, t10, t11, t20, t21, t30, t31;
                    asm volatile("ds_read_b64_tr_b16 %0, %1" : "=v"(t00) : "v"(vc));
                    asm volatile("ds_read_b64_tr_b16 %0, %1" : "=v"(t01) : "v"(vc + 256));
                    asm volatile("ds_read_b64_tr_b16 %0, %1" : "=v"(t10) : "v"(vc + 2048));
                    asm volatile("ds_read_b64_tr_b16 %0, %1" : "=v"(t11) : "v"(vc + 2304));
                    asm volatile("ds_read_b64_tr_b16 %0, %1" : "=v"(t20) : "v"(vc + 4096));
                    asm volatile("ds_read_b64_tr_b16 %0, %1" : "=v"(t21) : "v"(vc + 4352));
                    asm volatile("ds_read_b64_tr_b16 %0, %1" : "=v"(t30) : "v"(vc + 6144));
                    asm volatile("ds_read_b64_tr_b16 %0, %1" : "=v"(t31) : "v"(vc + 6400));
                    short8v ap;
                    ap[0] = f2bf(p[2 * ks][0]);     ap[1] = f2bf(p[2 * ks][1]);
                    ap[2] = f2bf(p[2 * ks][2]);     ap[3] = f2bf(p[2 * ks][3]);
                    ap[4] = f2bf(p[2 * ks + 1][0]); ap[5] = f2bf(p[2 * ks + 1][1]);
                    ap[6] = f2bf(p[2 * ks + 1][2]); ap[7] = f2bf(p[2 * ks + 1][3]);
                    asm volatile("s_waitcnt lgkmcnt(0)" ::: "memory");
                    __builtin_amdgcn_sched_barrier(0);
                    short8v bv0 = __builtin_shufflevector(t00, t01, 0, 1, 2, 3, 4, 5, 6, 7);
                    short8v bv1 = __builtin_shufflevector(t10, t11, 0, 1, 2, 3, 4, 5, 6, 7);
                    short8v bv2 = __builtin_shufflevector(t20, t21, 0, 1, 2, 3, 4, 5, 6, 7);
                    short8v bv3 = __builtin_shufflevector(t30, t31, 0, 1, 2, 3, 4, 5, 6, 7);
                    O0 = __builtin_amdgcn_mfma_f32_16x16x32_bf16(ap, bv0, O0, 0, 0, 0);
                    O1 = __builtin_amdgcn_mfma_f32_16x16x32_bf16(ap, bv1, O1, 0, 0, 0);
                    O2 = __builtin_amdgcn_mfma_f32_16x16x32_bf16(ap, bv2, O2, 0, 0, 0);
                    O3 = __builtin_amdgcn_mfma_f32_16x16x32_bf16(ap, bv3, O3, 0, 0, 0);
                }
            }
        }
        // ---- epilogue: normalize (redistribute 1/l via shfl) + store ----
        const int b  = bh >> 4;
        const int hh = bh & 15;
        short* orow = attn_out +
            ((size_t)(b * S_LEN) + qt * 64 + w * 16) * D_MODEL + hh * 64;
        float linv = 1.f / lrow;
#pragma unroll
        for (int r = 0; r < 4; ++r) {
            float inv = __shfl(linv, quad * 4 + r);
            short* prw = orow + (size_t)(quad * 4 + r) * D_MODEL;
            prw[0  + col] = f2bf(O0[r] * inv);
            prw[16 + col] = f2bf(O1[r] * inv);
            prw[32 + col] = f2bf(O2[r] * inv);
            prw[48 + col] = f2bf(O3[r] * inv);
        }
    }
}

// ---------------------------------------------------------------------------
extern "C" void kernel_launch(void* const* d_in, const int* in_sizes, int n_in,
                              void* d_out, int out_size, void* d_ws, size_t ws_size,
                              hipStream_t stream) {
    const float* x    = (const float*)d_in[0];
    const float* qU   = (const float*)d_in[1];
    const float* qV   = (const float*)d_in[2];
    const float* kU   = (const float*)d_in[3];
    const float* kV   = (const float*)d_in[4];
    const float* vU   = (const float*)d_in[5];
    const float* vV   = (const float*)d_in[6];
    const float* qlg  = (const float*)d_in[7];
    const float* klg  = (const float*)d_in[8];
    const float* vlg  = (const float*)d_in[9];
    const float* outw = (const float*)d_in[10];
    const int*   topk = (const int*)d_in[11];
    float* outp = (float*)d_out;

    char* ws = (char*)d_ws;
    short* xb   = (short*)(ws + 512);                    // 8 MB
    short* Uc   = xb + (size_t)MROWS * D_MODEL;          // 6 MB [3][1024][KCMAX]
    short* Vt   = Uc + (size_t)3 * D_MODEL * KCMAX;      // 6 MB [3][1024][KCMAX]
    short* wb   = Vt + (size_t)3 * D_MODEL * KCMAX;      // 2 MB
    short* Wt   = wb + (size_t)D_MODEL * D_MODEL;        // 6 MB [3][1024][1024]
    short* qkvb = Wt + (size_t)3 * D_MODEL * D_MODEL;    // 24 MB
    short* attnb = qkvb + (size_t)3 * MROWS * D_MODEL;   // 8 MB

    front_kernel<<<NCVBLK + 16 * 16 * 6, 256, 0, stream>>>(
        x, xb, outw, wb, qU, kU, vU, qV, kV, vV, qlg, klg, vlg, topk, Uc, Vt);
    gemm_weff_kernel<<<dim3(8, 8, 3), 256, 0, stream>>>(Vt, Uc, topk, Wt);
    gemm_qkv_kernel<<<dim3(32, 8, 3), 256, 0, stream>>>(xb, Wt, qkvb);
    attn_mfma_kernel<<<dim3(8, 64), 256, 0, stream>>>(qkvb, attnb);
    gemm_proj_kernel<<<dim3(32, 8), 256, 0, stream>>>(attnb, wb, outp);
}